// Round 10
// baseline (271.140 us; speedup 1.0000x reference)
//
#include <hip/hip_runtime.h>
#include <cstdint>
#include <cstddef>

#define B_DIM 16
#define N_DIM 2048
#define BN (B_DIM * N_DIM)          // 32768 rows per modality
#define QSCALE 0.18033688f          // 0.125 * log2(e): P = exp2(S')
#define PLANE ((size_t)BN * 64)     // elems per (jj,i) partial plane

typedef __attribute__((ext_vector_type(4))) float f32x4;
typedef __attribute__((ext_vector_type(16))) float f32x16;
typedef __attribute__((ext_vector_type(8))) __bf16 bf16x8;
typedef __attribute__((ext_vector_type(2))) unsigned int u32x2;

__device__ __forceinline__ unsigned short f2bf_rne(float f) {
    union { float f; unsigned int u; } v; v.f = f;
    unsigned int u = v.u;
    return (unsigned short)((u + 0x7fffu + ((u >> 16) & 1u)) >> 16);
}
__device__ __forceinline__ unsigned pk_rne(float a, float b) {
    return (unsigned)f2bf_rne(a) | ((unsigned)f2bf_rne(b) << 16);
}
// half_swap(a,b): res.x = {a.lo32, b.lo32}, res.y = {a.hi32, b.hi32}
__device__ __forceinline__ u32x2 half_swap(unsigned a, unsigned b) {
#if __has_builtin(__builtin_amdgcn_permlane32_swap)
    return __builtin_amdgcn_permlane32_swap(a, b, false, false);
#else
    unsigned pa = (unsigned)__shfl_xor((int)a, 32);
    unsigned pb = (unsigned)__shfl_xor((int)b, 32);
    bool hi = (threadIdx.x & 32) != 0;
    u32x2 r;
    r.x = hi ? pb : a;
    r.y = hi ? b : pa;
    return r;
#endif
}

// async global->LDS, 16B per lane; LDS dest = wave-uniform base + lane*16
__device__ __forceinline__ void g2lds16(const unsigned short* g, unsigned short* ldsbase) {
#if __has_builtin(__builtin_amdgcn_global_load_lds)
    __builtin_amdgcn_global_load_lds(
        (const __attribute__((address_space(1))) unsigned int*)g,
        (__attribute__((address_space(3))) unsigned int*)ldsbase,
        16, 0, 0);
#else
    int ln = threadIdx.x & 63;
    *(uint4*)(ldsbase + ln * 8) = *(const uint4*)g;
#endif
}

// ---------------------------------------------------------------------------
// prep (MFMA): Q = (x@W)*QSCALE, K = x@W^T  (bf16 rows), Vt = x^T (bf16, [m][b][d][n])
// (unchanged, verified)
// ---------------------------------------------------------------------------
__global__ __launch_bounds__(256) void prep_kernel(
    const float* __restrict__ x0, const float* __restrict__ x1, const float* __restrict__ x2,
    const float* __restrict__ w0, const float* __restrict__ w1, const float* __restrict__ w2,
    unsigned short* __restrict__ Qbf, unsigned short* __restrict__ Kbf,
    unsigned short* __restrict__ Vt)
{
    __shared__ float Wf[64 * 64];
    __shared__ float xs[128 * 68];

    int m    = blockIdx.x >> 8;
    int tile = blockIdx.x & 255;
    int row0 = tile * 128;
    int b    = row0 >> 11;
    int n0   = row0 & 2047;
    const float* x = (m == 0) ? x0 : (m == 1) ? x1 : x2;
    const float* W = (m == 0) ? w0 : (m == 1) ? w1 : w2;
    int tid = threadIdx.x;

    #pragma unroll
    for (int v = 0; v < 4; ++v) {
        int i4 = v * 256 + tid;
        *(f32x4*)&Wf[i4 * 4] = *(const f32x4*)&W[i4 * 4];
    }
    #pragma unroll
    for (int v = 0; v < 8; ++v) {
        int i4 = v * 256 + tid;
        int r = i4 >> 4, c = (i4 & 15) * 4;
        *(f32x4*)&xs[r * 68 + c] = *(const f32x4*)&x[(size_t)row0 * 64 + i4 * 4];
    }
    __syncthreads();

    int lane = tid & 63, wave = tid >> 6, lq = lane & 31, h = lane >> 5;

    bf16x8 wq[2][4], wk[2][4];
    #pragma unroll
    for (int mf = 0; mf < 2; ++mf)
        #pragma unroll
        for (int kc = 0; kc < 4; ++kc) {
            int e  = mf * 32 + lq;
            int d0 = kc * 16 + h * 8;
            unsigned uq[4], uk[4];
            #pragma unroll
            for (int t = 0; t < 4; ++t) {
                int d = d0 + 2 * t;
                uq[t] = pk_rne(Wf[d * 64 + e] * QSCALE, Wf[(d + 1) * 64 + e] * QSCALE);
                uk[t] = pk_rne(Wf[e * 64 + d], Wf[e * 64 + d + 1]);
            }
            uint4 ua; ua.x = uq[0]; ua.y = uq[1]; ua.z = uq[2]; ua.w = uq[3];
            uint4 ub; ub.x = uk[0]; ub.y = uk[1]; ub.z = uk[2]; ub.w = uk[3];
            wq[mf][kc] = __builtin_bit_cast(bf16x8, ua);
            wk[mf][kc] = __builtin_bit_cast(bf16x8, ub);
        }

    bf16x8 xb[4];
    #pragma unroll
    for (int kc = 0; kc < 4; ++kc) {
        const float* xr = &xs[(wave * 32 + lq) * 68 + kc * 16 + h * 8];
        unsigned u[4];
        #pragma unroll
        for (int t = 0; t < 4; ++t) u[t] = pk_rne(xr[2 * t], xr[2 * t + 1]);
        uint4 ua; ua.x = u[0]; ua.y = u[1]; ua.z = u[2]; ua.w = u[3];
        xb[kc] = __builtin_bit_cast(bf16x8, ua);
    }

    f32x16 Qt[2], Kt[2];
    #pragma unroll
    for (int r = 0; r < 16; ++r) { Qt[0][r] = 0.f; Qt[1][r] = 0.f; Kt[0][r] = 0.f; Kt[1][r] = 0.f; }
    #pragma unroll
    for (int kc = 0; kc < 4; ++kc) {
        #pragma unroll
        for (int mf = 0; mf < 2; ++mf) {
            Qt[mf] = __builtin_amdgcn_mfma_f32_32x32x16_bf16(wq[mf][kc], xb[kc], Qt[mf], 0, 0, 0);
            Kt[mf] = __builtin_amdgcn_mfma_f32_32x32x16_bf16(wk[mf][kc], xb[kc], Kt[mf], 0, 0, 0);
        }
    }

    size_t rowidx = (size_t)m * BN + row0 + wave * 32 + lq;
    unsigned short* qdst = Qbf + rowidx * 64 + h * 32;
    unsigned short* kdst = Kbf + rowidx * 64 + h * 32;
    #pragma unroll
    for (int s = 0; s < 4; ++s) {
        unsigned q00 = pk_rne(Qt[0][4 * s], Qt[0][4 * s + 1]);
        unsigned q01 = pk_rne(Qt[0][4 * s + 2], Qt[0][4 * s + 3]);
        unsigned q10 = pk_rne(Qt[1][4 * s], Qt[1][4 * s + 1]);
        unsigned q11 = pk_rne(Qt[1][4 * s + 2], Qt[1][4 * s + 3]);
        u32x2 a = half_swap(q00, q10);
        u32x2 c = half_swap(q01, q11);
        uint4 w; w.x = a.x; w.y = c.x; w.z = a.y; w.w = c.y;
        *(uint4*)&qdst[s * 8] = w;

        unsigned k00 = pk_rne(Kt[0][4 * s], Kt[0][4 * s + 1]);
        unsigned k01 = pk_rne(Kt[0][4 * s + 2], Kt[0][4 * s + 3]);
        unsigned k10 = pk_rne(Kt[1][4 * s], Kt[1][4 * s + 1]);
        unsigned k11 = pk_rne(Kt[1][4 * s + 2], Kt[1][4 * s + 3]);
        u32x2 a2 = half_swap(k00, k10);
        u32x2 c2 = half_swap(k01, k11);
        uint4 w2; w2.x = a2.x; w2.y = c2.x; w2.z = a2.y; w2.w = c2.y;
        *(uint4*)&kdst[s * 8] = w2;
    }

    int d  = tid & 63;
    int ng = tid >> 6;
    unsigned short* vdst = Vt + ((size_t)(m * B_DIM + b) * 64 + d) * 2048 + n0 + ng * 32;
    #pragma unroll
    for (int s = 0; s < 4; ++s) {
        uint4 w;
        w.x = pk_rne(xs[(ng * 32 + 8 * s + 0) * 68 + d], xs[(ng * 32 + 8 * s + 1) * 68 + d]);
        w.y = pk_rne(xs[(ng * 32 + 8 * s + 2) * 68 + d], xs[(ng * 32 + 8 * s + 3) * 68 + d]);
        w.z = pk_rne(xs[(ng * 32 + 8 * s + 4) * 68 + d], xs[(ng * 32 + 8 * s + 5) * 68 + d]);
        w.w = pk_rne(xs[(ng * 32 + 8 * s + 6) * 68 + d], xs[(ng * 32 + 8 * s + 7) * 68 + d]);
        *(uint4*)&vdst[s * 8] = w;
    }
}

// ---------------------------------------------------------------------------
// attention: block = one (pair, b, 256-q tile); 4 waves x 64 q-rows each.
// Triple-buffered LDS, DMA 1 tile ahead, one barrier per tile. Stage order
// tuned to HIDE LDS READ LATENCY:
//   [issue kfr reads] -> exp/pack/swap(g-1) -> [issue vfr reads] -> QK(g) -> PV(g-1)
// ---------------------------------------------------------------------------
__global__ __launch_bounds__(256, 3) void attn_kernel(
    const unsigned short* __restrict__ Qbf,
    const unsigned short* __restrict__ Kbf,
    const unsigned short* __restrict__ Vt,
    unsigned short* __restrict__ part)
{
    __shared__ unsigned short Ks[3][4096];   // [key][d], XOR-chunk swizzled
    __shared__ unsigned short Vs[3][4096];   // [d][key], XOR-chunk swizzled

    int blk = blockIdx.x;                    // 768 = 6 pairs * 16 b * 8 qt
    int qt  = blk & 7;
    int b   = (blk >> 3) & 15;
    int p   = blk >> 7;
    int i   = p >> 1, jj = p & 1;
    int j   = i + 1 + jj; if (j >= 3) j -= 3;
    int q0  = qt * 256;

    int tid = threadIdx.x, wave = tid >> 6, lane = tid & 63;
    int lq = lane & 31, h = lane >> 5;

    const unsigned short* Kg = Kbf + ((size_t)j * BN + b * N_DIM) * 64;
    const unsigned short* Vg = Vt + (size_t)(j * B_DIM + b) * 64 * 2048;

    // staging geometry (verified): swizzle on global side
    int rK   = wave * 16 + (lane >> 3);
    int sw8  = ((lane & 7) ^ ((lane >> 3) & 7)) * 8;
    size_t gkOff0 = (size_t)rK * 64 + sw8;
    size_t gkOff1 = (size_t)(rK + 8) * 64 + sw8;
    size_t gvOff0 = (size_t)rK * 2048 + sw8;
    size_t gvOff1 = (size_t)(rK + 8) * 2048 + sw8;

    auto stage = [&](int buf, int kt) {
        const unsigned short* gk = Kg + (size_t)kt * 4096;
        const unsigned short* gv = Vg + kt * 64;
        g2lds16(gk + gkOff0, &Ks[buf][wave * 1024]);
        g2lds16(gk + gkOff1, &Ks[buf][wave * 1024 + 512]);
        g2lds16(gv + gvOff0, &Vs[buf][wave * 1024]);
        g2lds16(gv + gvOff1, &Vs[buf][wave * 1024 + 512]);
    };

    // prologue: stage tiles 0 and 1
    stage(0, 0);
    stage(1, 1);

    // Q B-frags (block-constant)
    const unsigned short* Qg = Qbf + ((size_t)i * BN + b * N_DIM + q0 + wave * 64) * 64;
    bf16x8 qf[2][4];
    #pragma unroll
    for (int qi = 0; qi < 2; ++qi)
        #pragma unroll
        for (int kc = 0; kc < 4; ++kc)
            qf[qi][kc] = __builtin_bit_cast(bf16x8,
                *(const uint4*)&Qg[(qi * 32 + lq) * 64 + kc * 16 + h * 8]);

    f32x16 O[2][2];                          // [df][qi]
    #pragma unroll
    for (int r = 0; r < 16; ++r) { O[0][0][r] = 0.f; O[0][1][r] = 0.f; O[1][0][r] = 0.f; O[1][1][r] = 0.f; }
    float lsum[2] = {0.f, 0.f};

    __syncthreads();    // publishes tiles 0,1

    int key0 = lq;      // key row (kf=0) / base for reads

    // pipeline prime: QK of stage g=0 (tile 0, kf 0)
    f32x16 st[2];
    {
        const unsigned short* Kb = Ks[0];
        bf16x8 kfr[4];
        #pragma unroll
        for (int kc = 0; kc < 4; ++kc)
            kfr[kc] = __builtin_bit_cast(bf16x8,
                *(const uint4*)&Kb[key0 * 64 + (((2 * kc + h) ^ (key0 & 7)) * 8)]);
        #pragma unroll
        for (int qi = 0; qi < 2; ++qi) {
            f32x16 acc;
            #pragma unroll
            for (int r = 0; r < 16; ++r) acc[r] = 0.f;
            #pragma unroll
            for (int kc = 0; kc < 4; ++kc)
                acc = __builtin_amdgcn_mfma_f32_32x32x16_bf16(kfr[kc], qf[qi][kc], acc, 0, 0, 0);
            st[qi] = acc;
        }
    }

    for (int g = 1; g < 64; ++g) {
        int kt = g >> 1, kf = g & 1;
        if (kf == 0) {
            __syncthreads();                        // one barrier per tile
            if (kt < 31) stage((kt + 1) % 3, kt + 1);
        }

        // ---- (1) issue K-frag reads for QK(g) ----
        const unsigned short* Kb = Ks[kt % 3];
        int key = kf * 32 + lq;
        bf16x8 kfr[4];
        #pragma unroll
        for (int kc = 0; kc < 4; ++kc)
            kfr[kc] = __builtin_bit_cast(bf16x8,
                *(const uint4*)&Kb[key * 64 + (((2 * kc + h) ^ (key & 7)) * 8)]);

        // ---- (2) exp/pack/half-swap of stage g-1 -> pf (hides kfr latency) ----
        bf16x8 pf[2][2];                            // [qi][c]
        #pragma unroll
        for (int qi = 0; qi < 2; ++qi) {
            unsigned pkk[4][2];
            #pragma unroll
            for (int s = 0; s < 4; ++s) {
                float e0 = __builtin_amdgcn_exp2f(st[qi][4 * s + 0]);
                float e1 = __builtin_amdgcn_exp2f(st[qi][4 * s + 1]);
                float e2 = __builtin_amdgcn_exp2f(st[qi][4 * s + 2]);
                float e3 = __builtin_amdgcn_exp2f(st[qi][4 * s + 3]);
                lsum[qi] += (e0 + e1) + (e2 + e3);
                pkk[s][0] = __builtin_amdgcn_perm(
                    __builtin_bit_cast(unsigned, e1), __builtin_bit_cast(unsigned, e0), 0x07060302u);
                pkk[s][1] = __builtin_amdgcn_perm(
                    __builtin_bit_cast(unsigned, e3), __builtin_bit_cast(unsigned, e2), 0x07060302u);
            }
            #pragma unroll
            for (int c = 0; c < 2; ++c) {
                u32x2 rr0 = half_swap(pkk[2 * c][0], pkk[2 * c + 1][0]);
                u32x2 rr1 = half_swap(pkk[2 * c][1], pkk[2 * c + 1][1]);
                uint4 t; t.x = rr0.x; t.y = rr1.x; t.z = rr0.y; t.w = rr1.y;
                pf[qi][c] = __builtin_bit_cast(bf16x8, t);
            }
        }

        // ---- (3) issue V-frag reads for PV(g-1) ----
        int gp = g - 1, kfp = gp & 1;
        const unsigned short* Vb = Vs[(gp >> 1) % 3];
        bf16x8 vfr[2][2];                           // [c][df]
        #pragma unroll
        for (int c = 0; c < 2; ++c) {
            int kcpv = 2 * kfp + c;
            #pragma unroll
            for (int df = 0; df < 2; ++df) {
                int d = df * 32 + lq;
                vfr[c][df] = __builtin_bit_cast(bf16x8,
                    *(const uint4*)&Vb[d * 64 + (((2 * kcpv + h) ^ (d & 7)) * 8)]);
            }
        }

        // ---- (4) QK of stage g (hides vfr latency) ----
        #pragma unroll
        for (int qi = 0; qi < 2; ++qi) {
            f32x16 acc;
            #pragma unroll
            for (int r = 0; r < 16; ++r) acc[r] = 0.f;
            #pragma unroll
            for (int kc = 0; kc < 4; ++kc)
                acc = __builtin_amdgcn_mfma_f32_32x32x16_bf16(kfr[kc], qf[qi][kc], acc, 0, 0, 0);
            st[qi] = acc;
        }

        // ---- (5) PV of stage g-1: pure MFMA ----
        #pragma unroll
        for (int c = 0; c < 2; ++c)
            #pragma unroll
            for (int df = 0; df < 2; ++df) {
                O[df][0] = __builtin_amdgcn_mfma_f32_32x32x16_bf16(vfr[c][df], pf[0][c], O[df][0], 0, 0, 0);
                O[df][1] = __builtin_amdgcn_mfma_f32_32x32x16_bf16(vfr[c][df], pf[1][c], O[df][1], 0, 0, 0);
            }
    }

    // ---- drain: exp/pack/swap + PV of last stage (tile 31, kf 1) ----
    {
        bf16x8 pf[2][2];
        #pragma unroll
        for (int qi = 0; qi < 2; ++qi) {
            unsigned pkk[4][2];
            #pragma unroll
            for (int s = 0; s < 4; ++s) {
                float e0 = __builtin_amdgcn_exp2f(st[qi][4 * s + 0]);
                float e1 = __builtin_amdgcn_exp2f(st[qi][4 * s + 1]);
                float e2 = __builtin_amdgcn_exp2f(st[qi][4 * s + 2]);
                float e3 = __builtin_amdgcn_exp2f(st[qi][4 * s + 3]);
                lsum[qi] += (e0 + e1) + (e2 + e3);
                pkk[s][0] = __builtin_amdgcn_perm(
                    __builtin_bit_cast(unsigned, e1), __builtin_bit_cast(unsigned, e0), 0x07060302u);
                pkk[s][1] = __builtin_amdgcn_perm(
                    __builtin_bit_cast(unsigned, e3), __builtin_bit_cast(unsigned, e2), 0x07060302u);
            }
            #pragma unroll
            for (int c = 0; c < 2; ++c) {
                u32x2 rr0 = half_swap(pkk[2 * c][0], pkk[2 * c + 1][0]);
                u32x2 rr1 = half_swap(pkk[2 * c][1], pkk[2 * c + 1][1]);
                uint4 t; t.x = rr0.x; t.y = rr1.x; t.z = rr0.y; t.w = rr1.y;
                pf[qi][c] = __builtin_bit_cast(bf16x8, t);
            }
        }
        const unsigned short* Vb = Vs[31 % 3];
        #pragma unroll
        for (int c = 0; c < 2; ++c) {
            int kcpv = 2 * 1 + c;
            #pragma unroll
            for (int df = 0; df < 2; ++df) {
                int d = df * 32 + lq;
                bf16x8 vfr = __builtin_bit_cast(bf16x8,
                    *(const uint4*)&Vb[d * 64 + (((2 * kcpv + h) ^ (d & 7)) * 8)]);
                O[df][0] = __builtin_amdgcn_mfma_f32_32x32x16_bf16(vfr, pf[0][c], O[df][0], 0, 0, 0);
                O[df][1] = __builtin_amdgcn_mfma_f32_32x32x16_bf16(vfr, pf[1][c], O[df][1], 0, 0, 0);
            }
        }
    }

    // epilogue: normalize, half-swap to row layout, store bf16 partial rows
    #pragma unroll
    for (int qi = 0; qi < 2; ++qi) {
        float l = lsum[qi];
        l += __shfl_xor(l, 32);
        float inv = 1.0f / l;
        #pragma unroll
        for (int r = 0; r < 16; ++r) { O[0][qi][r] *= inv; O[1][qi][r] *= inv; }

        unsigned short* dst = part + ((size_t)jj * 3 + i) * PLANE
            + (size_t)(b * N_DIM + q0 + wave * 64 + qi * 32 + lq) * 64 + h * 32;
        #pragma unroll
        for (int s = 0; s < 4; ++s) {
            unsigned t00 = pk_rne(O[0][qi][4 * s], O[0][qi][4 * s + 1]);
            unsigned t01 = pk_rne(O[0][qi][4 * s + 2], O[0][qi][4 * s + 3]);
            unsigned t10 = pk_rne(O[1][qi][4 * s], O[1][qi][4 * s + 1]);
            unsigned t11 = pk_rne(O[1][qi][4 * s + 2], O[1][qi][4 * s + 3]);
            u32x2 a = half_swap(t00, t10);
            u32x2 c = half_swap(t01, t11);
            uint4 w; w.x = a.x; w.y = c.x; w.z = a.y; w.w = c.y;
            *(uint4*)&dst[s * 8] = w;
        }
    }
}

// ---------------------------------------------------------------------------
// reduce: out = (1/3) * sum of 6 bf16 partial planes
// ---------------------------------------------------------------------------
__global__ __launch_bounds__(256) void reduce_kernel(
    const unsigned short* __restrict__ part, float* __restrict__ out)
{
    size_t e = ((size_t)blockIdx.x * 256 + threadIdx.x) * 4;
    float a0 = 0.f, a1 = 0.f, a2 = 0.f, a3 = 0.f;
    #pragma unroll
    for (int q = 0; q < 6; ++q) {
        const unsigned short* pp = part + (size_t)q * PLANE + e;
        unsigned u0 = *(const unsigned*)&pp[0];
        unsigned u1 = *(const unsigned*)&pp[2];
        a0 += __builtin_bit_cast(float, u0 << 16);
        a1 += __builtin_bit_cast(float, u0 & 0xffff0000u);
        a2 += __builtin_bit_cast(float, u1 << 16);
        a3 += __builtin_bit_cast(float, u1 & 0xffff0000u);
    }
    f32x4 v;
    v.x = a0 * (1.0f / 3.0f); v.y = a1 * (1.0f / 3.0f);
    v.z = a2 * (1.0f / 3.0f); v.w = a3 * (1.0f / 3.0f);
    *(f32x4*)&out[e] = v;
}

extern "C" void kernel_launch(void* const* d_in, const int* in_sizes, int n_in,
                              void* d_out, int out_size, void* d_ws, size_t ws_size,
                              hipStream_t stream)
{
    const float* x0 = (const float*)d_in[0];
    const float* x1 = (const float*)d_in[1];
    const float* x2 = (const float*)d_in[2];
    const float* w0 = (const float*)d_in[3];
    const float* w1 = (const float*)d_in[4];
    const float* w2 = (const float*)d_in[5];
    float* out = (float*)d_out;

    size_t nElem = (size_t)3 * BN * 64;
    unsigned short* Qbf = (unsigned short*)d_ws;
    unsigned short* Kbf = Qbf + nElem;
    unsigned short* Vt  = Kbf + nElem;
    unsigned short* part = Vt + nElem;      // 6 planes * BN*64 bf16

    hipLaunchKernelGGL(prep_kernel, dim3(3 * (BN / 128)), dim3(256), 0, stream,
                       x0, x1, x2, w0, w1, w2, Qbf, Kbf, Vt);
    hipLaunchKernelGGL(attn_kernel, dim3(6 * B_DIM * (N_DIM / 256)), dim3(256), 0, stream,
                       Qbf, Kbf, Vt, part);
    hipLaunchKernelGGL(reduce_kernel, dim3((BN * 64 / 4) / 256), dim3(256), 0, stream,
                       part, out);
}

// Round 11
// 204.915 us; speedup vs baseline: 1.3232x; 1.3232x over previous
//
#include <hip/hip_runtime.h>
#include <cstdint>
#include <cstddef>

#define B_DIM 16
#define N_DIM 2048
#define BN (B_DIM * N_DIM)          // 32768 rows per modality
#define QSCALE 0.18033688f          // 0.125 * log2(e): P = exp2(S')
#define PLANE ((size_t)BN * 64)     // elems per (jj,i) partial plane
#define MBPLANE ((size_t)N_DIM * 64) // elems per (modality,batch) tensor block

typedef __attribute__((ext_vector_type(4))) float f32x4;
typedef __attribute__((ext_vector_type(16))) float f32x16;
typedef __attribute__((ext_vector_type(8))) __bf16 bf16x8;
typedef __attribute__((ext_vector_type(2))) unsigned int u32x2;

__device__ __forceinline__ unsigned short f2bf_rne(float f) {
    union { float f; unsigned int u; } v; v.f = f;
    unsigned int u = v.u;
    return (unsigned short)((u + 0x7fffu + ((u >> 16) & 1u)) >> 16);
}
__device__ __forceinline__ unsigned pk_rne(float a, float b) {
    return (unsigned)f2bf_rne(a) | ((unsigned)f2bf_rne(b) << 16);
}
// half_swap(a,b): res.x = {a.lo32, b.lo32}, res.y = {a.hi32, b.hi32}
__device__ __forceinline__ u32x2 half_swap(unsigned a, unsigned b) {
#if __has_builtin(__builtin_amdgcn_permlane32_swap)
    return __builtin_amdgcn_permlane32_swap(a, b, false, false);
#else
    unsigned pa = (unsigned)__shfl_xor((int)a, 32);
    unsigned pb = (unsigned)__shfl_xor((int)b, 32);
    bool hi = (threadIdx.x & 32) != 0;
    u32x2 r;
    r.x = hi ? pb : a;
    r.y = hi ? b : pa;
    return r;
#endif
}

// async global->LDS, 16B per lane; LDS dest = wave-uniform base + lane*16
__device__ __forceinline__ void g2lds16(const unsigned short* g, unsigned short* ldsbase) {
#if __has_builtin(__builtin_amdgcn_global_load_lds)
    __builtin_amdgcn_global_load_lds(
        (const __attribute__((address_space(1))) unsigned int*)g,
        (__attribute__((address_space(3))) unsigned int*)ldsbase,
        16, 0, 0);
#else
    int ln = threadIdx.x & 63;
    *(uint4*)(ldsbase + ln * 8) = *(const uint4*)g;
#endif
}

// ---------------------------------------------------------------------------
// prep (MFMA): Q = (x@W)*QSCALE, K = x@W^T, V = x^T — all emitted in TILED
// slab layouts (pure address permutation of the verified math):
//   Q: [m][b][g=q/64][qi=(q>>5)&1][chunk 0..7][lq=q&31][8elem]
//   K: [m][b][kt=key/64][chunk 0..7][key&63][8elem]      (chunk = d/8)
//   V: [m][b][kt][chunk=keygrp 0..7][d 0..63][8 keys]    (x^T slabs)
// ---------------------------------------------------------------------------
__global__ __launch_bounds__(256) void prep_kernel(
    const float* __restrict__ x0, const float* __restrict__ x1, const float* __restrict__ x2,
    const float* __restrict__ w0, const float* __restrict__ w1, const float* __restrict__ w2,
    unsigned short* __restrict__ Qbf, unsigned short* __restrict__ Kbf,
    unsigned short* __restrict__ Vt)
{
    __shared__ float Wf[64 * 64];
    __shared__ float xs[128 * 68];

    int m    = blockIdx.x >> 8;
    int tile = blockIdx.x & 255;
    int row0 = tile * 128;
    int b    = row0 >> 11;
    int n0   = row0 & 2047;
    const float* x = (m == 0) ? x0 : (m == 1) ? x1 : x2;
    const float* W = (m == 0) ? w0 : (m == 1) ? w1 : w2;
    int tid = threadIdx.x;

    #pragma unroll
    for (int v = 0; v < 4; ++v) {
        int i4 = v * 256 + tid;
        *(f32x4*)&Wf[i4 * 4] = *(const f32x4*)&W[i4 * 4];
    }
    #pragma unroll
    for (int v = 0; v < 8; ++v) {
        int i4 = v * 256 + tid;
        int r = i4 >> 4, c = (i4 & 15) * 4;
        *(f32x4*)&xs[r * 68 + c] = *(const f32x4*)&x[(size_t)row0 * 64 + i4 * 4];
    }
    __syncthreads();

    int lane = tid & 63, wave = tid >> 6, lq = lane & 31, h = lane >> 5;

    bf16x8 wq[2][4], wk[2][4];
    #pragma unroll
    for (int mf = 0; mf < 2; ++mf)
        #pragma unroll
        for (int kc = 0; kc < 4; ++kc) {
            int e  = mf * 32 + lq;
            int d0 = kc * 16 + h * 8;
            unsigned uq[4], uk[4];
            #pragma unroll
            for (int t = 0; t < 4; ++t) {
                int d = d0 + 2 * t;
                uq[t] = pk_rne(Wf[d * 64 + e] * QSCALE, Wf[(d + 1) * 64 + e] * QSCALE);
                uk[t] = pk_rne(Wf[e * 64 + d], Wf[e * 64 + d + 1]);
            }
            uint4 ua; ua.x = uq[0]; ua.y = uq[1]; ua.z = uq[2]; ua.w = uq[3];
            uint4 ub; ub.x = uk[0]; ub.y = uk[1]; ub.z = uk[2]; ub.w = uk[3];
            wq[mf][kc] = __builtin_bit_cast(bf16x8, ua);
            wk[mf][kc] = __builtin_bit_cast(bf16x8, ub);
        }

    bf16x8 xb[4];
    #pragma unroll
    for (int kc = 0; kc < 4; ++kc) {
        const float* xr = &xs[(wave * 32 + lq) * 68 + kc * 16 + h * 8];
        unsigned u[4];
        #pragma unroll
        for (int t = 0; t < 4; ++t) u[t] = pk_rne(xr[2 * t], xr[2 * t + 1]);
        uint4 ua; ua.x = u[0]; ua.y = u[1]; ua.z = u[2]; ua.w = u[3];
        xb[kc] = __builtin_bit_cast(bf16x8, ua);
    }

    f32x16 Qt[2], Kt[2];
    #pragma unroll
    for (int r = 0; r < 16; ++r) { Qt[0][r] = 0.f; Qt[1][r] = 0.f; Kt[0][r] = 0.f; Kt[1][r] = 0.f; }
    #pragma unroll
    for (int kc = 0; kc < 4; ++kc) {
        #pragma unroll
        for (int mf = 0; mf < 2; ++mf) {
            Qt[mf] = __builtin_amdgcn_mfma_f32_32x32x16_bf16(wq[mf][kc], xb[kc], Qt[mf], 0, 0, 0);
            Kt[mf] = __builtin_amdgcn_mfma_f32_32x32x16_bf16(wk[mf][kc], xb[kc], Kt[mf], 0, 0, 0);
        }
    }

    // ---- tiled stores -------------------------------------------------------
    size_t mbBase = ((size_t)m * B_DIM + b) * MBPLANE;
    int nn  = n0 + wave * 32 + lq;        // q/key index within (m,b)
    int g   = nn >> 6;                    // 64-row group
    int qi  = (nn >> 5) & 1;
    int ktp = nn >> 6, keyp = nn & 63;
    unsigned short* qb = Qbf + mbBase + (size_t)(g * 2 + qi) * 2048 + lq * 8;   // + c*256
    unsigned short* kb = Kbf + mbBase + (size_t)ktp * 4096 + keyp * 8;          // + c*512

    #pragma unroll
    for (int s = 0; s < 4; ++s) {
        int c = 4 * h + s;                // elem-chunk index (d-chunk)
        unsigned q00 = pk_rne(Qt[0][4 * s], Qt[0][4 * s + 1]);
        unsigned q01 = pk_rne(Qt[0][4 * s + 2], Qt[0][4 * s + 3]);
        unsigned q10 = pk_rne(Qt[1][4 * s], Qt[1][4 * s + 1]);
        unsigned q11 = pk_rne(Qt[1][4 * s + 2], Qt[1][4 * s + 3]);
        u32x2 a = half_swap(q00, q10);
        u32x2 cc = half_swap(q01, q11);
        uint4 w; w.x = a.x; w.y = cc.x; w.z = a.y; w.w = cc.y;
        *(uint4*)&qb[c * 256] = w;

        unsigned k00 = pk_rne(Kt[0][4 * s], Kt[0][4 * s + 1]);
        unsigned k01 = pk_rne(Kt[0][4 * s + 2], Kt[0][4 * s + 3]);
        unsigned k10 = pk_rne(Kt[1][4 * s], Kt[1][4 * s + 1]);
        unsigned k11 = pk_rne(Kt[1][4 * s + 2], Kt[1][4 * s + 3]);
        u32x2 a2 = half_swap(k00, k10);
        u32x2 c2 = half_swap(k01, k11);
        uint4 w2; w2.x = a2.x; w2.y = c2.x; w2.z = a2.y; w2.w = c2.y;
        *(uint4*)&kb[c * 512] = w2;
    }

    // V slabs: thread owns d = tid&63, key-range ng*32..+32
    int d  = tid & 63;
    int ng = tid >> 6;
    #pragma unroll
    for (int s = 0; s < 4; ++s) {
        int keystart = n0 + ng * 32 + 8 * s;
        int ktv = keystart >> 6;
        int cv  = (keystart & 63) >> 3;
        uint4 w;
        int rb = ng * 32 + 8 * s;
        w.x = pk_rne(xs[(rb + 0) * 68 + d], xs[(rb + 1) * 68 + d]);
        w.y = pk_rne(xs[(rb + 2) * 68 + d], xs[(rb + 3) * 68 + d]);
        w.z = pk_rne(xs[(rb + 4) * 68 + d], xs[(rb + 5) * 68 + d]);
        w.w = pk_rne(xs[(rb + 6) * 68 + d], xs[(rb + 7) * 68 + d]);
        *(uint4*)&Vt[mbBase + (size_t)(ktv * 8 + cv) * 512 + d * 8] = w;
    }
}

// ---------------------------------------------------------------------------
// attention: R7 pipeline verbatim (quad-buffered LDS, DMA 1 tile ahead, one
// barrier per tile, exp/pack(g-1) -> QK(g) -> PV(g-1)), but with slab-tiled
// layouts: conflict-minimal LDS reads, contiguous DMA, no XOR swizzle.
// ---------------------------------------------------------------------------
__global__ __launch_bounds__(256, 2) void attn_kernel(
    const unsigned short* __restrict__ Qbf,
    const unsigned short* __restrict__ Kbf,
    const unsigned short* __restrict__ Vt,
    unsigned short* __restrict__ part)
{
    __shared__ unsigned short Ks[4][4096];   // 8 slabs x [key 0..63][8elem]
    __shared__ unsigned short Vs[4][4096];   // 8 slabs x [d 0..63][8 keys]

    int blk = blockIdx.x;                    // 768 = 6 pairs * 16 b * 8 qt
    int qt  = blk & 7;
    int b   = (blk >> 3) & 15;
    int p   = blk >> 7;
    int i   = p >> 1, jj = p & 1;
    int j   = i + 1 + jj; if (j >= 3) j -= 3;

    int tid = threadIdx.x, wave = tid >> 6, lane = tid & 63;
    int lq = lane & 31, h = lane >> 5;

    const unsigned short* KgT = Kbf + ((size_t)j * B_DIM + b) * MBPLANE;
    const unsigned short* VgT = Vt  + ((size_t)j * B_DIM + b) * MBPLANE;
    const unsigned short* QgT = Qbf + ((size_t)i * B_DIM + b) * MBPLANE;

    // wave stages slabs {2w, 2w+1} of K and V; global side contiguous 1KB
    int c0 = wave * 2;
    auto stage = [&](int buf, int kt) {
        const unsigned short* gk = KgT + ((size_t)(kt * 8 + c0) * 64 + lane) * 8;
        const unsigned short* gv = VgT + ((size_t)(kt * 8 + c0) * 64 + lane) * 8;
        g2lds16(gk,       &Ks[buf][c0 * 512]);
        g2lds16(gk + 512, &Ks[buf][c0 * 512 + 512]);
        g2lds16(gv,       &Vs[buf][c0 * 512]);
        g2lds16(gv + 512, &Vs[buf][c0 * 512 + 512]);
    };

    // prologue: stage tiles 0 and 1
    stage(0, 0);
    stage(1, 1);

    // Q B-frags (block-constant), tiled & coalesced
    int g0 = qt * 4 + wave;
    bf16x8 qf[2][4];
    #pragma unroll
    for (int qi = 0; qi < 2; ++qi)
        #pragma unroll
        for (int kc = 0; kc < 4; ++kc)
            qf[qi][kc] = __builtin_bit_cast(bf16x8, *(const uint4*)&QgT[
                (size_t)(g0 * 2 + qi) * 2048 + (kc * 2 + h) * 256 + lq * 8]);

    f32x16 O[2][2];                          // [df][qi]
    #pragma unroll
    for (int r = 0; r < 16; ++r) { O[0][0][r] = 0.f; O[0][1][r] = 0.f; O[1][0][r] = 0.f; O[1][1][r] = 0.f; }
    float lsum[2] = {0.f, 0.f};

    __syncthreads();    // publishes tiles 0,1

    // pipeline prime: QK of stage g=0 (tile 0, kf 0)
    f32x16 st[2];
    {
        const unsigned short* Kb = Ks[0];
        bf16x8 kfr[4];
        #pragma unroll
        for (int kc = 0; kc < 4; ++kc)
            kfr[kc] = __builtin_bit_cast(bf16x8,
                *(const uint4*)&Kb[(2 * kc + h) * 512 + lq * 8]);
        #pragma unroll
        for (int qi = 0; qi < 2; ++qi) {
            f32x16 acc;
            #pragma unroll
            for (int r = 0; r < 16; ++r) acc[r] = 0.f;
            #pragma unroll
            for (int kc = 0; kc < 4; ++kc)
                acc = __builtin_amdgcn_mfma_f32_32x32x16_bf16(kfr[kc], qf[qi][kc], acc, 0, 0, 0);
            st[qi] = acc;
        }
    }

    for (int g = 1; g < 64; ++g) {
        int kt = g >> 1, kf = g & 1;
        if (kf == 0) {
            __syncthreads();                        // one barrier per tile
            if (kt < 31) stage((kt + 1) & 3, kt + 1);
        }

        // ---- exp/pack of stage g-1 (scores ready since last iteration) ----
        unsigned pkk[2][4][2];
        #pragma unroll
        for (int qi = 0; qi < 2; ++qi)
            #pragma unroll
            for (int s = 0; s < 4; ++s) {
                float e0 = __builtin_amdgcn_exp2f(st[qi][4 * s + 0]);
                float e1 = __builtin_amdgcn_exp2f(st[qi][4 * s + 1]);
                float e2 = __builtin_amdgcn_exp2f(st[qi][4 * s + 2]);
                float e3 = __builtin_amdgcn_exp2f(st[qi][4 * s + 3]);
                lsum[qi] += (e0 + e1) + (e2 + e3);
                pkk[qi][s][0] = __builtin_amdgcn_perm(
                    __builtin_bit_cast(unsigned, e1), __builtin_bit_cast(unsigned, e0), 0x07060302u);
                pkk[qi][s][1] = __builtin_amdgcn_perm(
                    __builtin_bit_cast(unsigned, e3), __builtin_bit_cast(unsigned, e2), 0x07060302u);
            }

        // ---- QK of stage g (independent of the exp above) ----
        {
            const unsigned short* Kb = Ks[kt & 3];
            bf16x8 kfr[4];
            #pragma unroll
            for (int kc = 0; kc < 4; ++kc)
                kfr[kc] = __builtin_bit_cast(bf16x8,
                    *(const uint4*)&Kb[(2 * kc + h) * 512 + (kf * 32 + lq) * 8]);
            #pragma unroll
            for (int qi = 0; qi < 2; ++qi) {
                f32x16 acc;
                #pragma unroll
                for (int r = 0; r < 16; ++r) acc[r] = 0.f;
                #pragma unroll
                for (int kc = 0; kc < 4; ++kc)
                    acc = __builtin_amdgcn_mfma_f32_32x32x16_bf16(kfr[kc], qf[qi][kc], acc, 0, 0, 0);
                st[qi] = acc;
            }
        }

        // ---- PV of stage g-1 ----
        {
            int gp = g - 1, kfp = gp & 1;
            const unsigned short* Vb = Vs[(gp >> 1) & 3];
            #pragma unroll
            for (int c = 0; c < 2; ++c) {
                bf16x8 pf[2];
                #pragma unroll
                for (int qi = 0; qi < 2; ++qi) {
                    u32x2 rr0 = half_swap(pkk[qi][2 * c][0], pkk[qi][2 * c + 1][0]);
                    u32x2 rr1 = half_swap(pkk[qi][2 * c][1], pkk[qi][2 * c + 1][1]);
                    uint4 t; t.x = rr0.x; t.y = rr1.x; t.z = rr0.y; t.w = rr1.y;
                    pf[qi] = __builtin_bit_cast(bf16x8, t);
                }
                int kcpv = 2 * kfp + c;
                #pragma unroll
                for (int df = 0; df < 2; ++df) {
                    bf16x8 vfr = __builtin_bit_cast(bf16x8,
                        *(const uint4*)&Vb[(2 * kcpv + h) * 512 + (df * 32 + lq) * 8]);
                    O[df][0] = __builtin_amdgcn_mfma_f32_32x32x16_bf16(vfr, pf[0], O[df][0], 0, 0, 0);
                    O[df][1] = __builtin_amdgcn_mfma_f32_32x32x16_bf16(vfr, pf[1], O[df][1], 0, 0, 0);
                }
            }
        }
    }

    // ---- drain: exp/pack + PV of last stage (tile 31, kf 1) ----
    {
        unsigned pkk[2][4][2];
        #pragma unroll
        for (int qi = 0; qi < 2; ++qi)
            #pragma unroll
            for (int s = 0; s < 4; ++s) {
                float e0 = __builtin_amdgcn_exp2f(st[qi][4 * s + 0]);
                float e1 = __builtin_amdgcn_exp2f(st[qi][4 * s + 1]);
                float e2 = __builtin_amdgcn_exp2f(st[qi][4 * s + 2]);
                float e3 = __builtin_amdgcn_exp2f(st[qi][4 * s + 3]);
                lsum[qi] += (e0 + e1) + (e2 + e3);
                pkk[qi][s][0] = __builtin_amdgcn_perm(
                    __builtin_bit_cast(unsigned, e1), __builtin_bit_cast(unsigned, e0), 0x07060302u);
                pkk[qi][s][1] = __builtin_amdgcn_perm(
                    __builtin_bit_cast(unsigned, e3), __builtin_bit_cast(unsigned, e2), 0x07060302u);
            }
        const unsigned short* Vb = Vs[31 & 3];
        #pragma unroll
        for (int c = 0; c < 2; ++c) {
            bf16x8 pf[2];
            #pragma unroll
            for (int qi = 0; qi < 2; ++qi) {
                u32x2 rr0 = half_swap(pkk[qi][2 * c][0], pkk[qi][2 * c + 1][0]);
                u32x2 rr1 = half_swap(pkk[qi][2 * c][1], pkk[qi][2 * c + 1][1]);
                uint4 t; t.x = rr0.x; t.y = rr1.x; t.z = rr0.y; t.w = rr1.y;
                pf[qi] = __builtin_bit_cast(bf16x8, t);
            }
            int kcpv = 2 * 1 + c;
            #pragma unroll
            for (int df = 0; df < 2; ++df) {
                bf16x8 vfr = __builtin_bit_cast(bf16x8,
                    *(const uint4*)&Vb[(2 * kcpv + h) * 512 + (df * 32 + lq) * 8]);
                O[df][0] = __builtin_amdgcn_mfma_f32_32x32x16_bf16(vfr, pf[0], O[df][0], 0, 0, 0);
                O[df][1] = __builtin_amdgcn_mfma_f32_32x32x16_bf16(vfr, pf[1], O[df][1], 0, 0, 0);
            }
        }
    }

    // epilogue: normalize, half-swap to row layout, store bf16 partial rows
    int q0 = qt * 256;
    #pragma unroll
    for (int qi = 0; qi < 2; ++qi) {
        float l = lsum[qi];
        l += __shfl_xor(l, 32);
        float inv = 1.0f / l;
        #pragma unroll
        for (int r = 0; r < 16; ++r) { O[0][qi][r] *= inv; O[1][qi][r] *= inv; }

        unsigned short* dst = part + ((size_t)jj * 3 + i) * PLANE
            + (size_t)(b * N_DIM + q0 + wave * 64 + qi * 32 + lq) * 64 + h * 32;
        #pragma unroll
        for (int s = 0; s < 4; ++s) {
            unsigned t00 = pk_rne(O[0][qi][4 * s], O[0][qi][4 * s + 1]);
            unsigned t01 = pk_rne(O[0][qi][4 * s + 2], O[0][qi][4 * s + 3]);
            unsigned t10 = pk_rne(O[1][qi][4 * s], O[1][qi][4 * s + 1]);
            unsigned t11 = pk_rne(O[1][qi][4 * s + 2], O[1][qi][4 * s + 3]);
            u32x2 a = half_swap(t00, t10);
            u32x2 c = half_swap(t01, t11);
            uint4 w; w.x = a.x; w.y = c.x; w.z = a.y; w.w = c.y;
            *(uint4*)&dst[s * 8] = w;
        }
    }
}

// ---------------------------------------------------------------------------
// reduce: out = (1/3) * sum of 6 bf16 partial planes
// ---------------------------------------------------------------------------
__global__ __launch_bounds__(256) void reduce_kernel(
    const unsigned short* __restrict__ part, float* __restrict__ out)
{
    size_t e = ((size_t)blockIdx.x * 256 + threadIdx.x) * 4;
    float a0 = 0.f, a1 = 0.f, a2 = 0.f, a3 = 0.f;
    #pragma unroll
    for (int q = 0; q < 6; ++q) {
        const unsigned short* pp = part + (size_t)q * PLANE + e;
        unsigned u0 = *(const unsigned*)&pp[0];
        unsigned u1 = *(const unsigned*)&pp[2];
        a0 += __builtin_bit_cast(float, u0 << 16);
        a1 += __builtin_bit_cast(float, u0 & 0xffff0000u);
        a2 += __builtin_bit_cast(float, u1 << 16);
        a3 += __builtin_bit_cast(float, u1 & 0xffff0000u);
    }
    f32x4 v;
    v.x = a0 * (1.0f / 3.0f); v.y = a1 * (1.0f / 3.0f);
    v.z = a2 * (1.0f / 3.0f); v.w = a3 * (1.0f / 3.0f);
    *(f32x4*)&out[e] = v;
}

extern "C" void kernel_launch(void* const* d_in, const int* in_sizes, int n_in,
                              void* d_out, int out_size, void* d_ws, size_t ws_size,
                              hipStream_t stream)
{
    const float* x0 = (const float*)d_in[0];
    const float* x1 = (const float*)d_in[1];
    const float* x2 = (const float*)d_in[2];
    const float* w0 = (const float*)d_in[3];
    const float* w1 = (const float*)d_in[4];
    const float* w2 = (const float*)d_in[5];
    float* out = (float*)d_out;

    size_t nElem = (size_t)3 * BN * 64;
    unsigned short* Qbf = (unsigned short*)d_ws;
    unsigned short* Kbf = Qbf + nElem;
    unsigned short* Vt  = Kbf + nElem;
    unsigned short* part = Vt + nElem;      // 6 planes * BN*64 bf16

    hipLaunchKernelGGL(prep_kernel, dim3(3 * (BN / 128)), dim3(256), 0, stream,
                       x0, x1, x2, w0, w1, w2, Qbf, Kbf, Vt);
    hipLaunchKernelGGL(attn_kernel, dim3(6 * B_DIM * (N_DIM / 256)), dim3(256), 0, stream,
                       Qbf, Kbf, Vt, part);
    hipLaunchKernelGGL(reduce_kernel, dim3((BN * 64 / 4) / 256), dim3(256), 0, stream,
                       part, out);
}

// Round 12
// 200.687 us; speedup vs baseline: 1.3511x; 1.0211x over previous
//
#include <hip/hip_runtime.h>
#include <cstdint>
#include <cstddef>

#define B_DIM 16
#define N_DIM 2048
#define BN (B_DIM * N_DIM)          // 32768 rows per modality
#define QSCALE 0.18033688f          // 0.125 * log2(e): P = exp2(S')
#define PLANE ((size_t)BN * 64)     // elems per (jj,i) partial plane
#define MBPLANE ((size_t)N_DIM * 64) // elems per (modality,batch) tensor block

typedef __attribute__((ext_vector_type(4))) float f32x4;
typedef __attribute__((ext_vector_type(16))) float f32x16;
typedef __attribute__((ext_vector_type(8))) __bf16 bf16x8;
typedef __attribute__((ext_vector_type(2))) unsigned int u32x2;

__device__ __forceinline__ unsigned short f2bf_rne(float f) {
    union { float f; unsigned int u; } v; v.f = f;
    unsigned int u = v.u;
    return (unsigned short)((u + 0x7fffu + ((u >> 16) & 1u)) >> 16);
}
__device__ __forceinline__ unsigned pk_rne(float a, float b) {
    return (unsigned)f2bf_rne(a) | ((unsigned)f2bf_rne(b) << 16);
}
// half_swap(a,b): res.x = {a.lo32, b.lo32}, res.y = {a.hi32, b.hi32}
__device__ __forceinline__ u32x2 half_swap(unsigned a, unsigned b) {
#if __has_builtin(__builtin_amdgcn_permlane32_swap)
    return __builtin_amdgcn_permlane32_swap(a, b, false, false);
#else
    unsigned pa = (unsigned)__shfl_xor((int)a, 32);
    unsigned pb = (unsigned)__shfl_xor((int)b, 32);
    bool hi = (threadIdx.x & 32) != 0;
    u32x2 r;
    r.x = hi ? pb : a;
    r.y = hi ? b : pa;
    return r;
#endif
}

// async global->LDS, 16B per lane; LDS dest = wave-uniform base + lane*16
__device__ __forceinline__ void g2lds16(const unsigned short* g, unsigned short* ldsbase) {
#if __has_builtin(__builtin_amdgcn_global_load_lds)
    __builtin_amdgcn_global_load_lds(
        (const __attribute__((address_space(1))) unsigned int*)g,
        (__attribute__((address_space(3))) unsigned int*)ldsbase,
        16, 0, 0);
#else
    int ln = threadIdx.x & 63;
    *(uint4*)(ldsbase + ln * 8) = *(const uint4*)g;
#endif
}

// ---------------------------------------------------------------------------
// prep (MFMA): Q = (x@W)*QSCALE, K = x@W^T, V = x^T — all emitted in TILED
// slab layouts (verified in R11):
//   Q: [m][b][g=q/64][qi=(q>>5)&1][chunk 0..7][lq=q&31][8elem]
//   K: [m][b][kt=key/64][chunk 0..7][key&63][8elem]      (chunk = d/8)
//   V: [m][b][kt][chunk=keygrp 0..7][d 0..63][8 keys]    (x^T slabs)
// ---------------------------------------------------------------------------
__global__ __launch_bounds__(256) void prep_kernel(
    const float* __restrict__ x0, const float* __restrict__ x1, const float* __restrict__ x2,
    const float* __restrict__ w0, const float* __restrict__ w1, const float* __restrict__ w2,
    unsigned short* __restrict__ Qbf, unsigned short* __restrict__ Kbf,
    unsigned short* __restrict__ Vt)
{
    __shared__ float Wf[64 * 64];
    __shared__ float xs[128 * 68];

    int m    = blockIdx.x >> 8;
    int tile = blockIdx.x & 255;
    int row0 = tile * 128;
    int b    = row0 >> 11;
    int n0   = row0 & 2047;
    const float* x = (m == 0) ? x0 : (m == 1) ? x1 : x2;
    const float* W = (m == 0) ? w0 : (m == 1) ? w1 : w2;
    int tid = threadIdx.x;

    #pragma unroll
    for (int v = 0; v < 4; ++v) {
        int i4 = v * 256 + tid;
        *(f32x4*)&Wf[i4 * 4] = *(const f32x4*)&W[i4 * 4];
    }
    #pragma unroll
    for (int v = 0; v < 8; ++v) {
        int i4 = v * 256 + tid;
        int r = i4 >> 4, c = (i4 & 15) * 4;
        *(f32x4*)&xs[r * 68 + c] = *(const f32x4*)&x[(size_t)row0 * 64 + i4 * 4];
    }
    __syncthreads();

    int lane = tid & 63, wave = tid >> 6, lq = lane & 31, h = lane >> 5;

    bf16x8 wq[2][4], wk[2][4];
    #pragma unroll
    for (int mf = 0; mf < 2; ++mf)
        #pragma unroll
        for (int kc = 0; kc < 4; ++kc) {
            int e  = mf * 32 + lq;
            int d0 = kc * 16 + h * 8;
            unsigned uq[4], uk[4];
            #pragma unroll
            for (int t = 0; t < 4; ++t) {
                int d = d0 + 2 * t;
                uq[t] = pk_rne(Wf[d * 64 + e] * QSCALE, Wf[(d + 1) * 64 + e] * QSCALE);
                uk[t] = pk_rne(Wf[e * 64 + d], Wf[e * 64 + d + 1]);
            }
            uint4 ua; ua.x = uq[0]; ua.y = uq[1]; ua.z = uq[2]; ua.w = uq[3];
            uint4 ub; ub.x = uk[0]; ub.y = uk[1]; ub.z = uk[2]; ub.w = uk[3];
            wq[mf][kc] = __builtin_bit_cast(bf16x8, ua);
            wk[mf][kc] = __builtin_bit_cast(bf16x8, ub);
        }

    bf16x8 xb[4];
    #pragma unroll
    for (int kc = 0; kc < 4; ++kc) {
        const float* xr = &xs[(wave * 32 + lq) * 68 + kc * 16 + h * 8];
        unsigned u[4];
        #pragma unroll
        for (int t = 0; t < 4; ++t) u[t] = pk_rne(xr[2 * t], xr[2 * t + 1]);
        uint4 ua; ua.x = u[0]; ua.y = u[1]; ua.z = u[2]; ua.w = u[3];
        xb[kc] = __builtin_bit_cast(bf16x8, ua);
    }

    f32x16 Qt[2], Kt[2];
    #pragma unroll
    for (int r = 0; r < 16; ++r) { Qt[0][r] = 0.f; Qt[1][r] = 0.f; Kt[0][r] = 0.f; Kt[1][r] = 0.f; }
    #pragma unroll
    for (int kc = 0; kc < 4; ++kc) {
        #pragma unroll
        for (int mf = 0; mf < 2; ++mf) {
            Qt[mf] = __builtin_amdgcn_mfma_f32_32x32x16_bf16(wq[mf][kc], xb[kc], Qt[mf], 0, 0, 0);
            Kt[mf] = __builtin_amdgcn_mfma_f32_32x32x16_bf16(wk[mf][kc], xb[kc], Kt[mf], 0, 0, 0);
        }
    }

    // ---- tiled stores -------------------------------------------------------
    size_t mbBase = ((size_t)m * B_DIM + b) * MBPLANE;
    int nn  = n0 + wave * 32 + lq;        // q/key index within (m,b)
    int g   = nn >> 6;                    // 64-row group
    int qi  = (nn >> 5) & 1;
    int ktp = nn >> 6, keyp = nn & 63;
    unsigned short* qb = Qbf + mbBase + (size_t)(g * 2 + qi) * 2048 + lq * 8;   // + c*256
    unsigned short* kb = Kbf + mbBase + (size_t)ktp * 4096 + keyp * 8;          // + c*512

    #pragma unroll
    for (int s = 0; s < 4; ++s) {
        int c = 4 * h + s;                // elem-chunk index (d-chunk)
        unsigned q00 = pk_rne(Qt[0][4 * s], Qt[0][4 * s + 1]);
        unsigned q01 = pk_rne(Qt[0][4 * s + 2], Qt[0][4 * s + 3]);
        unsigned q10 = pk_rne(Qt[1][4 * s], Qt[1][4 * s + 1]);
        unsigned q11 = pk_rne(Qt[1][4 * s + 2], Qt[1][4 * s + 3]);
        u32x2 a = half_swap(q00, q10);
        u32x2 cc = half_swap(q01, q11);
        uint4 w; w.x = a.x; w.y = cc.x; w.z = a.y; w.w = cc.y;
        *(uint4*)&qb[c * 256] = w;

        unsigned k00 = pk_rne(Kt[0][4 * s], Kt[0][4 * s + 1]);
        unsigned k01 = pk_rne(Kt[0][4 * s + 2], Kt[0][4 * s + 3]);
        unsigned k10 = pk_rne(Kt[1][4 * s], Kt[1][4 * s + 1]);
        unsigned k11 = pk_rne(Kt[1][4 * s + 2], Kt[1][4 * s + 3]);
        u32x2 a2 = half_swap(k00, k10);
        u32x2 c2 = half_swap(k01, k11);
        uint4 w2; w2.x = a2.x; w2.y = c2.x; w2.z = a2.y; w2.w = c2.y;
        *(uint4*)&kb[c * 512] = w2;
    }

    // V slabs: thread owns d = tid&63, key-range ng*32..+32
    int d  = tid & 63;
    int ng = tid >> 6;
    #pragma unroll
    for (int s = 0; s < 4; ++s) {
        int keystart = n0 + ng * 32 + 8 * s;
        int ktv = keystart >> 6;
        int cv  = (keystart & 63) >> 3;
        uint4 w;
        int rb = ng * 32 + 8 * s;
        w.x = pk_rne(xs[(rb + 0) * 68 + d], xs[(rb + 1) * 68 + d]);
        w.y = pk_rne(xs[(rb + 2) * 68 + d], xs[(rb + 3) * 68 + d]);
        w.z = pk_rne(xs[(rb + 4) * 68 + d], xs[(rb + 5) * 68 + d]);
        w.w = pk_rne(xs[(rb + 6) * 68 + d], xs[(rb + 7) * 68 + d]);
        *(uint4*)&Vt[mbBase + (size_t)(ktv * 8 + cv) * 512 + d * 8] = w;
    }
}

// ---------------------------------------------------------------------------
// attention: R11 structure with TRIPLE-buffered LDS (48 KB -> 3 blocks/CU,
// 3 waves/SIMD). DMA 1 tile ahead, one barrier per tile, slab layouts
// (zero bank conflicts), pipeline: exp/pack(g-1) -> QK(g) -> PV(g-1).
// ---------------------------------------------------------------------------
__global__ __launch_bounds__(256, 3) void attn_kernel(
    const unsigned short* __restrict__ Qbf,
    const unsigned short* __restrict__ Kbf,
    const unsigned short* __restrict__ Vt,
    unsigned short* __restrict__ part)
{
    __shared__ unsigned short Ks[3][4096];   // 8 slabs x [key 0..63][8elem]
    __shared__ unsigned short Vs[3][4096];   // 8 slabs x [d 0..63][8 keys]

    int blk = blockIdx.x;                    // 768 = 6 pairs * 16 b * 8 qt
    int qt  = blk & 7;
    int b   = (blk >> 3) & 15;
    int p   = blk >> 7;
    int i   = p >> 1, jj = p & 1;
    int j   = i + 1 + jj; if (j >= 3) j -= 3;

    int tid = threadIdx.x, wave = tid >> 6, lane = tid & 63;
    int lq = lane & 31, h = lane >> 5;

    const unsigned short* KgT = Kbf + ((size_t)j * B_DIM + b) * MBPLANE;
    const unsigned short* VgT = Vt  + ((size_t)j * B_DIM + b) * MBPLANE;
    const unsigned short* QgT = Qbf + ((size_t)i * B_DIM + b) * MBPLANE;

    // wave stages slabs {2w, 2w+1} of K and V; global side contiguous 1KB
    int c0 = wave * 2;
    auto stage = [&](int buf, int kt) {
        const unsigned short* gk = KgT + ((size_t)(kt * 8 + c0) * 64 + lane) * 8;
        const unsigned short* gv = VgT + ((size_t)(kt * 8 + c0) * 64 + lane) * 8;
        g2lds16(gk,       &Ks[buf][c0 * 512]);
        g2lds16(gk + 512, &Ks[buf][c0 * 512 + 512]);
        g2lds16(gv,       &Vs[buf][c0 * 512]);
        g2lds16(gv + 512, &Vs[buf][c0 * 512 + 512]);
    };

    // prologue: stage tiles 0 and 1
    stage(0, 0);
    stage(1, 1);

    // Q B-frags (block-constant), tiled & coalesced
    int g0 = qt * 4 + wave;
    bf16x8 qf[2][4];
    #pragma unroll
    for (int qi = 0; qi < 2; ++qi)
        #pragma unroll
        for (int kc = 0; kc < 4; ++kc)
            qf[qi][kc] = __builtin_bit_cast(bf16x8, *(const uint4*)&QgT[
                (size_t)(g0 * 2 + qi) * 2048 + (kc * 2 + h) * 256 + lq * 8]);

    f32x16 O[2][2];                          // [df][qi]
    #pragma unroll
    for (int r = 0; r < 16; ++r) { O[0][0][r] = 0.f; O[0][1][r] = 0.f; O[1][0][r] = 0.f; O[1][1][r] = 0.f; }
    float lsum[2] = {0.f, 0.f};

    __syncthreads();    // publishes tiles 0,1

    // pipeline prime: QK of stage g=0 (tile 0, kf 0)
    f32x16 st[2];
    {
        const unsigned short* Kb = Ks[0];
        bf16x8 kfr[4];
        #pragma unroll
        for (int kc = 0; kc < 4; ++kc)
            kfr[kc] = __builtin_bit_cast(bf16x8,
                *(const uint4*)&Kb[(2 * kc + h) * 512 + lq * 8]);
        #pragma unroll
        for (int qi = 0; qi < 2; ++qi) {
            f32x16 acc;
            #pragma unroll
            for (int r = 0; r < 16; ++r) acc[r] = 0.f;
            #pragma unroll
            for (int kc = 0; kc < 4; ++kc)
                acc = __builtin_amdgcn_mfma_f32_32x32x16_bf16(kfr[kc], qf[qi][kc], acc, 0, 0, 0);
            st[qi] = acc;
        }
    }

    for (int g = 1; g < 64; ++g) {
        int kt = g >> 1, kf = g & 1;
        if (kf == 0) {
            __syncthreads();                        // one barrier per tile
            if (kt < 31) stage((kt + 1) % 3, kt + 1);
        }

        // ---- exp/pack of stage g-1 (scores ready since last iteration) ----
        unsigned pkk[2][4][2];
        #pragma unroll
        for (int qi = 0; qi < 2; ++qi)
            #pragma unroll
            for (int s = 0; s < 4; ++s) {
                float e0 = __builtin_amdgcn_exp2f(st[qi][4 * s + 0]);
                float e1 = __builtin_amdgcn_exp2f(st[qi][4 * s + 1]);
                float e2 = __builtin_amdgcn_exp2f(st[qi][4 * s + 2]);
                float e3 = __builtin_amdgcn_exp2f(st[qi][4 * s + 3]);
                lsum[qi] += (e0 + e1) + (e2 + e3);
                pkk[qi][s][0] = __builtin_amdgcn_perm(
                    __builtin_bit_cast(unsigned, e1), __builtin_bit_cast(unsigned, e0), 0x07060302u);
                pkk[qi][s][1] = __builtin_amdgcn_perm(
                    __builtin_bit_cast(unsigned, e3), __builtin_bit_cast(unsigned, e2), 0x07060302u);
            }

        // ---- QK of stage g (independent of the exp above) ----
        {
            const unsigned short* Kb = Ks[kt % 3];
            bf16x8 kfr[4];
            #pragma unroll
            for (int kc = 0; kc < 4; ++kc)
                kfr[kc] = __builtin_bit_cast(bf16x8,
                    *(const uint4*)&Kb[(2 * kc + h) * 512 + (kf * 32 + lq) * 8]);
            #pragma unroll
            for (int qi = 0; qi < 2; ++qi) {
                f32x16 acc;
                #pragma unroll
                for (int r = 0; r < 16; ++r) acc[r] = 0.f;
                #pragma unroll
                for (int kc = 0; kc < 4; ++kc)
                    acc = __builtin_amdgcn_mfma_f32_32x32x16_bf16(kfr[kc], qf[qi][kc], acc, 0, 0, 0);
                st[qi] = acc;
            }
        }

        // ---- PV of stage g-1 ----
        {
            int gp = g - 1, kfp = gp & 1;
            const unsigned short* Vb = Vs[(gp >> 1) % 3];
            #pragma unroll
            for (int c = 0; c < 2; ++c) {
                bf16x8 pf[2];
                #pragma unroll
                for (int qi = 0; qi < 2; ++qi) {
                    u32x2 rr0 = half_swap(pkk[qi][2 * c][0], pkk[qi][2 * c + 1][0]);
                    u32x2 rr1 = half_swap(pkk[qi][2 * c][1], pkk[qi][2 * c + 1][1]);
                    uint4 t; t.x = rr0.x; t.y = rr1.x; t.z = rr0.y; t.w = rr1.y;
                    pf[qi] = __builtin_bit_cast(bf16x8, t);
                }
                int kcpv = 2 * kfp + c;
                #pragma unroll
                for (int df = 0; df < 2; ++df) {
                    bf16x8 vfr = __builtin_bit_cast(bf16x8,
                        *(const uint4*)&Vb[(2 * kcpv + h) * 512 + (df * 32 + lq) * 8]);
                    O[df][0] = __builtin_amdgcn_mfma_f32_32x32x16_bf16(vfr, pf[0], O[df][0], 0, 0, 0);
                    O[df][1] = __builtin_amdgcn_mfma_f32_32x32x16_bf16(vfr, pf[1], O[df][1], 0, 0, 0);
                }
            }
        }
    }

    // ---- drain: exp/pack + PV of last stage (tile 31, kf 1) ----
    {
        unsigned pkk[2][4][2];
        #pragma unroll
        for (int qi = 0; qi < 2; ++qi)
            #pragma unroll
            for (int s = 0; s < 4; ++s) {
                float e0 = __builtin_amdgcn_exp2f(st[qi][4 * s + 0]);
                float e1 = __builtin_amdgcn_exp2f(st[qi][4 * s + 1]);
                float e2 = __builtin_amdgcn_exp2f(st[qi][4 * s + 2]);
                float e3 = __builtin_amdgcn_exp2f(st[qi][4 * s + 3]);
                lsum[qi] += (e0 + e1) + (e2 + e3);
                pkk[qi][s][0] = __builtin_amdgcn_perm(
                    __builtin_bit_cast(unsigned, e1), __builtin_bit_cast(unsigned, e0), 0x07060302u);
                pkk[qi][s][1] = __builtin_amdgcn_perm(
                    __builtin_bit_cast(unsigned, e3), __builtin_bit_cast(unsigned, e2), 0x07060302u);
            }
        const unsigned short* Vb = Vs[31 % 3];
        #pragma unroll
        for (int c = 0; c < 2; ++c) {
            bf16x8 pf[2];
            #pragma unroll
            for (int qi = 0; qi < 2; ++qi) {
                u32x2 rr0 = half_swap(pkk[qi][2 * c][0], pkk[qi][2 * c + 1][0]);
                u32x2 rr1 = half_swap(pkk[qi][2 * c][1], pkk[qi][2 * c + 1][1]);
                uint4 t; t.x = rr0.x; t.y = rr1.x; t.z = rr0.y; t.w = rr1.y;
                pf[qi] = __builtin_bit_cast(bf16x8, t);
            }
            int kcpv = 2 * 1 + c;
            #pragma unroll
            for (int df = 0; df < 2; ++df) {
                bf16x8 vfr = __builtin_bit_cast(bf16x8,
                    *(const uint4*)&Vb[(2 * kcpv + h) * 512 + (df * 32 + lq) * 8]);
                O[df][0] = __builtin_amdgcn_mfma_f32_32x32x16_bf16(vfr, pf[0], O[df][0], 0, 0, 0);
                O[df][1] = __builtin_amdgcn_mfma_f32_32x32x16_bf16(vfr, pf[1], O[df][1], 0, 0, 0);
            }
        }
    }

    // epilogue: normalize, half-swap to row layout, store bf16 partial rows
    int q0 = qt * 256;
    #pragma unroll
    for (int qi = 0; qi < 2; ++qi) {
        float l = lsum[qi];
        l += __shfl_xor(l, 32);
        float inv = 1.0f / l;
        #pragma unroll
        for (int r = 0; r < 16; ++r) { O[0][qi][r] *= inv; O[1][qi][r] *= inv; }

        unsigned short* dst = part + ((size_t)jj * 3 + i) * PLANE
            + (size_t)(b * N_DIM + q0 + wave * 64 + qi * 32 + lq) * 64 + h * 32;
        #pragma unroll
        for (int s = 0; s < 4; ++s) {
            unsigned t00 = pk_rne(O[0][qi][4 * s], O[0][qi][4 * s + 1]);
            unsigned t01 = pk_rne(O[0][qi][4 * s + 2], O[0][qi][4 * s + 3]);
            unsigned t10 = pk_rne(O[1][qi][4 * s], O[1][qi][4 * s + 1]);
            unsigned t11 = pk_rne(O[1][qi][4 * s + 2], O[1][qi][4 * s + 3]);
            u32x2 a = half_swap(t00, t10);
            u32x2 c = half_swap(t01, t11);
            uint4 w; w.x = a.x; w.y = c.x; w.z = a.y; w.w = c.y;
            *(uint4*)&dst[s * 8] = w;
        }
    }
}

// ---------------------------------------------------------------------------
// reduce: out = (1/3) * sum of 6 bf16 partial planes
// ---------------------------------------------------------------------------
__global__ __launch_bounds__(256) void reduce_kernel(
    const unsigned short* __restrict__ part, float* __restrict__ out)
{
    size_t e = ((size_t)blockIdx.x * 256 + threadIdx.x) * 4;
    float a0 = 0.f, a1 = 0.f, a2 = 0.f, a3 = 0.f;
    #pragma unroll
    for (int q = 0; q < 6; ++q) {
        const unsigned short* pp = part + (size_t)q * PLANE + e;
        unsigned u0 = *(const unsigned*)&pp[0];
        unsigned u1 = *(const unsigned*)&pp[2];
        a0 += __builtin_bit_cast(float, u0 << 16);
        a1 += __builtin_bit_cast(float, u0 & 0xffff0000u);
        a2 += __builtin_bit_cast(float, u1 << 16);
        a3 += __builtin_bit_cast(float, u1 & 0xffff0000u);
    }
    f32x4 v;
    v.x = a0 * (1.0f / 3.0f); v.y = a1 * (1.0f / 3.0f);
    v.z = a2 * (1.0f / 3.0f); v.w = a3 * (1.0f / 3.0f);
    *(f32x4*)&out[e] = v;
}

extern "C" void kernel_launch(void* const* d_in, const int* in_sizes, int n_in,
                              void* d_out, int out_size, void* d_ws, size_t ws_size,
                              hipStream_t stream)
{
    const float* x0 = (const float*)d_in[0];
    const float* x1 = (const float*)d_in[1];
    const float* x2 = (const float*)d_in[2];
    const float* w0 = (const float*)d_in[3];
    const float* w1 = (const float*)d_in[4];
    const float* w2 = (const float*)d_in[5];
    float* out = (float*)d_out;

    size_t nElem = (size_t)3 * BN * 64;
    unsigned short* Qbf = (unsigned short*)d_ws;
    unsigned short* Kbf = Qbf + nElem;
    unsigned short* Vt  = Kbf + nElem;
    unsigned short* part = Vt + nElem;      // 6 planes * BN*64 bf16

    hipLaunchKernelGGL(prep_kernel, dim3(3 * (BN / 128)), dim3(256), 0, stream,
                       x0, x1, x2, w0, w1, w2, Qbf, Kbf, Vt);
    hipLaunchKernelGGL(attn_kernel, dim3(6 * B_DIM * (N_DIM / 256)), dim3(256), 0, stream,
                       Qbf, Kbf, Vt, part);
    hipLaunchKernelGGL(reduce_kernel, dim3((BN * 64 / 4) / 256), dim3(256), 0, stream,
                       part, out);
}